// Round 2
// baseline (159.367 us; speedup 1.0000x reference)
//
#include <hip/hip_runtime.h>

#define D_FEAT 128

// ================= fixed-capacity bucketing, 4B records, 4-edge ILP =================
//
// ws layout (words): cursor[N] | deg[N] | ovfcnt[1] | ovf[E] | rec[N*cap] (4B each)
// record = {src:16, w_q:16}; w in [0,1) -> 16-bit midpoint quant (err <= 2^-17).
// cap from ws_size (>=40 in practice); P(indeg > cap) ~ 0 for random dst, but the
// overflow list keeps any input exact.

__device__ __forceinline__ unsigned wq16(float f) {
    int q = (int)(f * 65536.0f);
    if (q < 0) q = 0;
    if (q > 65535) q = 65535;
    return (unsigned)q;
}

__global__ void bucket_multi_kernel(const int* __restrict__ src, const int* __restrict__ dst,
                                    const float* __restrict__ w,
                                    int* __restrict__ cursor, float* __restrict__ deg,
                                    int* __restrict__ ovfcnt, int* __restrict__ ovf,
                                    unsigned* __restrict__ rec, int cap,
                                    int E, const int* __restrict__ mode) {
    int t = blockIdx.x * blockDim.x + threadIdx.x;
    int base = t * 4;
    if (base >= E) return;
    bool m1 = (*mode == 1);
    if (base + 3 < E) {
        int4   s4 = ((const int4*)src)[t];
        int4   d4 = ((const int4*)dst)[t];
        float4 w4 = ((const float4*)w)[t];
        if (!m1) {
            atomicAdd(&deg[s4.x], 1.0f); atomicAdd(&deg[s4.y], 1.0f);
            atomicAdd(&deg[s4.z], 1.0f); atomicAdd(&deg[s4.w], 1.0f);
        }
        // 4 independent atomic chains issue back-to-back (latency overlap)
        int p0 = atomicAdd(&cursor[d4.x], 1);
        int p1 = atomicAdd(&cursor[d4.y], 1);
        int p2 = atomicAdd(&cursor[d4.z], 1);
        int p3 = atomicAdd(&cursor[d4.w], 1);
        unsigned r0 = ((unsigned)s4.x << 16) | wq16(w4.x);
        unsigned r1 = ((unsigned)s4.y << 16) | wq16(w4.y);
        unsigned r2 = ((unsigned)s4.z << 16) | wq16(w4.z);
        unsigned r3 = ((unsigned)s4.w << 16) | wq16(w4.w);
        if (p0 < cap) rec[(size_t)d4.x * cap + p0] = r0; else ovf[atomicAdd(ovfcnt, 1)] = base + 0;
        if (p1 < cap) rec[(size_t)d4.y * cap + p1] = r1; else ovf[atomicAdd(ovfcnt, 1)] = base + 1;
        if (p2 < cap) rec[(size_t)d4.z * cap + p2] = r2; else ovf[atomicAdd(ovfcnt, 1)] = base + 2;
        if (p3 < cap) rec[(size_t)d4.w * cap + p3] = r3; else ovf[atomicAdd(ovfcnt, 1)] = base + 3;
    } else {
        for (int e = base; e < E; ++e) {
            int s = src[e], d = dst[e];
            if (!m1) atomicAdd(&deg[s], 1.0f);
            int pos = atomicAdd(&cursor[d], 1);
            if (pos < cap) rec[(size_t)d * cap + pos] = ((unsigned)s << 16) | wq16(w[e]);
            else ovf[atomicAdd(ovfcnt, 1)] = e;
        }
    }
}

// 32 lanes per dst node; lane owns one float4 slice.
// Record row preloaded into 2 regs/lane (coalesced) and broadcast via __shfl ->
// the only memory op in the hot loop is the h-row load; 4-way unroll with 4
// independent accumulator sets -> 4 h loads in flight per lane. Mode unswitched
// so the m1 path has zero deg[] traffic.
__device__ __forceinline__ unsigned bcast_rec(unsigned r0, unsigned r1, int j) {
    unsigned lo = __shfl(r0, j & 31, 32);
    unsigned hi = __shfl(r1, j & 31, 32);
    return (j < 32) ? lo : hi;
}

__global__ void gather4_f32_kernel(const float* __restrict__ h,
                                   const int* __restrict__ cursor, const float* __restrict__ deg,
                                   const unsigned* __restrict__ rec, int cap,
                                   const int* __restrict__ ovfcnt, const int* __restrict__ ovf,
                                   const int* __restrict__ src, const int* __restrict__ dst,
                                   const float* __restrict__ w,
                                   float* __restrict__ out, int N, const int* __restrict__ mode) {
    long long gid = (long long)blockIdx.x * blockDim.x + threadIdx.x;
    int node = (int)(gid >> 5);
    int lane = (int)(gid & 31);
    if (node >= N) return;
    bool m1 = (*mode == 1);
    int cnt = cursor[node];
    int inb = cnt < cap ? cnt : cap;
    const unsigned* row = rec + (size_t)node * cap;
    // coalesced preload of the whole record row (cap <= 64 records)
    unsigned r0 = (lane < inb) ? row[lane] : 0u;
    unsigned r1 = (lane + 32 < inb) ? row[lane + 32] : 0u;

    const float4* h4 = (const float4*)h;
    float a0 = 0.f, a1 = 0.f, a2 = 0.f, a3 = 0.f;
    float b0 = 0.f, b1 = 0.f, b2 = 0.f, b3 = 0.f;
    float c0 = 0.f, c1 = 0.f, c2 = 0.f, c3 = 0.f;
    float d0 = 0.f, d1 = 0.f, d2 = 0.f, d3 = 0.f;

    int j = 0;
    if (m1) {
        const float Q = 1.52587890625e-05f;  // 2^-16
        for (; j + 3 < inb; j += 4) {
            unsigned m0 = bcast_rec(r0, r1, j);
            unsigned m1r = bcast_rec(r0, r1, j + 1);
            unsigned m2r = bcast_rec(r0, r1, j + 2);
            unsigned m3r = bcast_rec(r0, r1, j + 3);
            float sc0 = ((float)(m0 & 0xFFFFu) + 0.5f) * Q;
            float sc1 = ((float)(m1r & 0xFFFFu) + 0.5f) * Q;
            float sc2 = ((float)(m2r & 0xFFFFu) + 0.5f) * Q;
            float sc3 = ((float)(m3r & 0xFFFFu) + 0.5f) * Q;
            float4 v0 = h4[(size_t)(m0 >> 16) * 32 + lane];
            float4 v1 = h4[(size_t)(m1r >> 16) * 32 + lane];
            float4 v2 = h4[(size_t)(m2r >> 16) * 32 + lane];
            float4 v3 = h4[(size_t)(m3r >> 16) * 32 + lane];
            a0 += v0.x * sc0; a1 += v0.y * sc0; a2 += v0.z * sc0; a3 += v0.w * sc0;
            b0 += v1.x * sc1; b1 += v1.y * sc1; b2 += v1.z * sc1; b3 += v1.w * sc1;
            c0 += v2.x * sc2; c1 += v2.y * sc2; c2 += v2.z * sc2; c3 += v2.w * sc2;
            d0 += v3.x * sc3; d1 += v3.y * sc3; d2 += v3.z * sc3; d3 += v3.w * sc3;
        }
        for (; j < inb; ++j) {
            unsigned m0 = bcast_rec(r0, r1, j);
            float sc0 = ((float)(m0 & 0xFFFFu) + 0.5f) * Q;
            float4 v0 = h4[(size_t)(m0 >> 16) * 32 + lane];
            a0 += v0.x * sc0; a1 += v0.y * sc0; a2 += v0.z * sc0; a3 += v0.w * sc0;
        }
    } else {
        for (; j + 3 < inb; j += 4) {
            unsigned m0 = bcast_rec(r0, r1, j);
            unsigned m1r = bcast_rec(r0, r1, j + 1);
            unsigned m2r = bcast_rec(r0, r1, j + 2);
            unsigned m3r = bcast_rec(r0, r1, j + 3);
            int s0 = (int)(m0 >> 16), s1 = (int)(m1r >> 16);
            int s2 = (int)(m2r >> 16), s3 = (int)(m3r >> 16);
            float sc0 = rsqrtf(deg[s0]);
            float sc1 = rsqrtf(deg[s1]);
            float sc2 = rsqrtf(deg[s2]);
            float sc3 = rsqrtf(deg[s3]);
            float4 v0 = h4[(size_t)s0 * 32 + lane];
            float4 v1 = h4[(size_t)s1 * 32 + lane];
            float4 v2 = h4[(size_t)s2 * 32 + lane];
            float4 v3 = h4[(size_t)s3 * 32 + lane];
            a0 += v0.x * sc0; a1 += v0.y * sc0; a2 += v0.z * sc0; a3 += v0.w * sc0;
            b0 += v1.x * sc1; b1 += v1.y * sc1; b2 += v1.z * sc1; b3 += v1.w * sc1;
            c0 += v2.x * sc2; c1 += v2.y * sc2; c2 += v2.z * sc2; c3 += v2.w * sc2;
            d0 += v3.x * sc3; d1 += v3.y * sc3; d2 += v3.z * sc3; d3 += v3.w * sc3;
        }
        for (; j < inb; ++j) {
            unsigned m0 = bcast_rec(r0, r1, j);
            int s0 = (int)(m0 >> 16);
            float sc0 = rsqrtf(deg[s0]);
            float4 v0 = h4[(size_t)s0 * 32 + lane];
            a0 += v0.x * sc0; a1 += v0.y * sc0; a2 += v0.z * sc0; a3 += v0.w * sc0;
        }
    }

    a0 += b0 + c0 + d0; a1 += b1 + c1 + d1;
    a2 += b2 + c2 + d2; a3 += b3 + c3 + d3;

    if (cnt > cap) {                                  // exact overflow path (~never taken)
        int total = *ovfcnt;
        for (int k = 0; k < total; ++k) {
            int e = ovf[k];
            if (dst[e] == node) {
                int s = src[e];
                float sc = m1 ? w[e] : rsqrtf(deg[s]);
                float4 v = ((const float4*)(h + (long long)s * D_FEAT))[lane];
                a0 += v.x * sc; a1 += v.y * sc; a2 += v.z * sc; a3 += v.w * sc;
            }
        }
    }
    float fin = m1 ? 1.0f : rsqrtf(deg[node]);        // deg==0 -> inf, matches powf(0,-0.5)
    float4 r; r.x = a0 * fin; r.y = a1 * fin; r.z = a2 * fin; r.w = a3 * fin;
    ((float4*)(out + (long long)node * D_FEAT))[lane] = r;
}

// ================= PATH C: R8-proven 8B records (smaller ws) =================

__global__ void bucket_direct_kernel(const int* __restrict__ src, const int* __restrict__ dst,
                                     const float* __restrict__ w,
                                     int* __restrict__ cursor, float* __restrict__ deg,
                                     int* __restrict__ ovfcnt, int* __restrict__ ovf,
                                     uint2* __restrict__ epack, int cap,
                                     int E, const int* __restrict__ mode) {
    int e = blockIdx.x * blockDim.x + threadIdx.x;
    if (e >= E) return;
    bool m1 = (*mode == 1);
    int d = dst[e];
    int s = src[e];
    if (!m1) atomicAdd(&deg[s], 1.0f);
    int pos = atomicAdd(&cursor[d], 1);
    if (pos < cap) {
        float sc = m1 ? w[e] : 0.0f;
        epack[(size_t)d * cap + pos] = make_uint2((unsigned)s, __float_as_uint(sc));
    } else {
        ovf[atomicAdd(ovfcnt, 1)] = e;
    }
}

__global__ void gather_cap_kernel(const float* __restrict__ h,
                                  const int* __restrict__ cursor, const float* __restrict__ deg,
                                  const uint2* __restrict__ epack, int cap,
                                  const int* __restrict__ ovfcnt, const int* __restrict__ ovf,
                                  const int* __restrict__ src, const int* __restrict__ dst,
                                  const float* __restrict__ w,
                                  float* __restrict__ out, int N, const int* __restrict__ mode) {
    long long gid = (long long)blockIdx.x * blockDim.x + threadIdx.x;
    int node = (int)(gid >> 5);
    int lane = (int)(gid & 31);
    if (node >= N) return;
    bool m1 = (*mode == 1);
    int cnt = cursor[node];
    int inb = cnt < cap ? cnt : cap;
    const uint2* row = epack + (size_t)node * cap;
    float a0 = 0.f, a1 = 0.f, a2 = 0.f, a3 = 0.f;
    for (int j = 0; j < inb; ++j) {
        uint2 m = row[j];
        int s = (int)m.x;
        float sc = m1 ? __uint_as_float(m.y) : rsqrtf(deg[s]);
        float4 v = ((const float4*)(h + (long long)s * D_FEAT))[lane];
        a0 += v.x * sc; a1 += v.y * sc; a2 += v.z * sc; a3 += v.w * sc;
    }
    if (cnt > cap) {
        int total = *ovfcnt;
        for (int k = 0; k < total; ++k) {
            int e = ovf[k];
            if (dst[e] == node) {
                int s = src[e];
                float sc = m1 ? w[e] : rsqrtf(deg[s]);
                float4 v = ((const float4*)(h + (long long)s * D_FEAT))[lane];
                a0 += v.x * sc; a1 += v.y * sc; a2 += v.z * sc; a3 += v.w * sc;
            }
        }
    }
    float fin = m1 ? 1.0f : rsqrtf(deg[node]);
    float4 r; r.x = a0 * fin; r.y = a1 * fin; r.z = a2 * fin; r.w = a3 * fin;
    ((float4*)(out + (long long)node * D_FEAT))[lane] = r;
}

// ================= ultra-fallback: atomic scatter =================

__global__ void fb_deg_kernel(const int* __restrict__ src, float* __restrict__ deg,
                              int E, const int* __restrict__ mode) {
    if (*mode == 1) return;
    int e = blockIdx.x * blockDim.x + threadIdx.x;
    if (e < E) atomicAdd(&deg[src[e]], 1.0f);
}
__global__ void fb_norm_kernel(const float* __restrict__ deg, float* __restrict__ norm,
                               int N, const int* __restrict__ mode) {
    if (*mode == 1) return;
    int i = blockIdx.x * blockDim.x + threadIdx.x;
    if (i < N) norm[i] = rsqrtf(deg[i]);
}
__global__ void fb_scatter_kernel(const float* __restrict__ h, const float* __restrict__ w,
                                  const int* __restrict__ src, const int* __restrict__ dst,
                                  const float* __restrict__ norm, float* __restrict__ out,
                                  int E, const int* __restrict__ mode) {
    long long gid = (long long)blockIdx.x * blockDim.x + threadIdx.x;
    int e = (int)(gid >> 5);
    int lane = (int)(gid & 31);
    if (e >= E) return;
    int s = src[e], d = dst[e];
    float scale = (*mode == 1) ? w[e] : norm[s];
    float4 v = ((const float4*)(h + (long long)s * D_FEAT))[lane];
    float* op = out + (long long)d * D_FEAT + lane * 4;
    atomicAdd(op + 0, v.x * scale);
    atomicAdd(op + 1, v.y * scale);
    atomicAdd(op + 2, v.z * scale);
    atomicAdd(op + 3, v.w * scale);
}
__global__ void fb_scale_kernel(float* __restrict__ out, const float* __restrict__ norm,
                                int N, const int* __restrict__ mode) {
    if (*mode == 1) return;
    int idx = blockIdx.x * blockDim.x + threadIdx.x;
    int total = N * (D_FEAT / 4);
    if (idx >= total) return;
    int node = idx / (D_FEAT / 4);
    float4* op = (float4*)out + idx;
    float4 v = *op;
    float nn = norm[node];
    v.x *= nn; v.y *= nn; v.z *= nn; v.w *= nn;
    *op = v;
}

// ================= host =================

extern "C" void kernel_launch(void* const* d_in, const int* in_sizes, int n_in,
                              void* d_out, int out_size, void* d_ws, size_t ws_size,
                              hipStream_t stream) {
    const float* h    = (const float*)d_in[0];
    const float* w    = (const float*)d_in[1];
    const int*   src  = (const int*)d_in[2];
    const int*   dst  = (const int*)d_in[3];
    const int*   mode = (const int*)d_in[4];

    int ND = in_sizes[0];
    int E  = in_sizes[1];
    int N  = ND / D_FEAT;

    float* out = (float*)d_out;

    size_t ws_words    = ws_size / 4;
    size_t fixed_words = 2 * (size_t)N + 1 + (size_t)E;   // cursor, deg, ovfcnt, ovf
    size_t rec_off     = fixed_words;

    long capA = 0;
    if (ws_words > rec_off) capA = (long)((ws_words - rec_off) / (size_t)N);
    if (capA > 64) capA = 64;

    int*   cursor = (int*)d_ws;
    float* deg    = (float*)(cursor + N);
    int*   ovfcnt = (int*)(deg + N);
    int*   ovf    = ovfcnt + 1;

    if (N <= 65536 && capA >= 28) {
        unsigned* rec = (unsigned*)((int*)d_ws + rec_off);
        int cap = (int)capA;

        hipMemsetAsync(d_ws, 0, (2 * (size_t)N + 1) * sizeof(int), stream);

        int nthreads = (E + 3) / 4;
        bucket_multi_kernel<<<(nthreads + 255) / 256, 256, 0, stream>>>(
            src, dst, w, cursor, deg, ovfcnt, ovf, rec, cap, E, mode);

        long long gt = (long long)N * 32;
        gather4_f32_kernel<<<(int)((gt + 255) / 256), 256, 0, stream>>>(
            h, cursor, deg, rec, cap, ovfcnt, ovf, src, dst, w, out, N, mode);
        return;
    }

    // PATH C: 8B records (R8 structure)
    size_t epack_off = (fixed_words + 1) & ~(size_t)1;
    long capC = 0;
    if (ws_words > epack_off) capC = (long)((ws_words - epack_off) / (2 * (size_t)N));
    if (capC > 64) capC = 64;

    if (capC >= 8) {
        uint2* epack = (uint2*)((int*)d_ws + epack_off);
        hipMemsetAsync(d_ws, 0, (2 * (size_t)N + 1) * sizeof(int), stream);
        bucket_direct_kernel<<<(E + 255) / 256, 256, 0, stream>>>(
            src, dst, w, cursor, deg, ovfcnt, ovf, epack, (int)capC, E, mode);
        long long gt = (long long)N * 32;
        gather_cap_kernel<<<(int)((gt + 255) / 256), 256, 0, stream>>>(
            h, cursor, deg, epack, (int)capC, ovfcnt, ovf, src, dst, w, out, N, mode);
        return;
    }

    // ultra-fallback: atomic scatter
    float* degF  = (float*)d_ws;
    float* normF = degF + N;
    hipMemsetAsync(d_out, 0, (size_t)out_size * sizeof(float), stream);
    hipMemsetAsync(d_ws, 0, (size_t)N * sizeof(float), stream);
    fb_deg_kernel<<<(E + 255) / 256, 256, 0, stream>>>(src, degF, E, mode);
    fb_norm_kernel<<<(N + 255) / 256, 256, 0, stream>>>(degF, normF, N, mode);
    long long tt = (long long)E * 32;
    fb_scatter_kernel<<<(int)((tt + 255) / 256), 256, 0, stream>>>(h, w, src, dst,
                                                                   normF, out, E, mode);
    int st = N * (D_FEAT / 4);
    fb_scale_kernel<<<(st + 255) / 256, 256, 0, stream>>>(out, normF, N, mode);
}

// Round 3
// 153.372 us; speedup vs baseline: 1.0391x; 1.0391x over previous
//
#include <hip/hip_runtime.h>
#include <hip/hip_fp16.h>

#define D_FEAT 128

// ================= fixed-capacity bucketing + fp16 feature cache =================
//
// ws layout, fp16 path (words):
//   cursor[N] | deg[N] | ovfcnt[1] | ovf[E] | pad->16B | h16[N*64] | rec[N*cap]
// record = {src:16, w_q:16}; w in [0,1) -> 16-bit midpoint quant (err <= 2^-17).
// h cached as fp16 rows (256B): halves gather HBM bytes; fp16 roundoff adds
// ~5e-3 absmax vs 0.0625 tolerance. Overflow path re-reads f32 h (exact-ish).

__device__ __forceinline__ unsigned wq16(float f) {
    int q = (int)(f * 65536.0f);
    if (q < 0) q = 0;
    if (q > 65535) q = 65535;
    return (unsigned)q;
}

__device__ __forceinline__ unsigned h2u(__half2 v) {
    union { __half2 h; unsigned u; } cv; cv.h = v; return cv.u;
}
__device__ __forceinline__ float2 u2f2(unsigned u) {
    union { unsigned u; __half2 h; } cv; cv.u = u;
    return __half22float2(cv.h);
}

// ---- fused: [0, nBucketBlocks) buckets edges; rest converts h -> fp16 ----
__global__ void bucket_conv_kernel(const float* __restrict__ h,
                                   const int* __restrict__ src, const int* __restrict__ dst,
                                   const float* __restrict__ w,
                                   int* __restrict__ cursor, float* __restrict__ deg,
                                   int* __restrict__ ovfcnt, int* __restrict__ ovf,
                                   unsigned* __restrict__ rec, int cap,
                                   uint4* __restrict__ h16,
                                   int E, int nBucketBlocks, int nGroups8,
                                   const int* __restrict__ mode) {
    if ((int)blockIdx.x >= nBucketBlocks) {
        // ---------- convert: 8 floats -> 8 halfs per thread ----------
        int i = (blockIdx.x - nBucketBlocks) * blockDim.x + threadIdx.x;
        if (i >= nGroups8) return;
        const float4* hf4 = (const float4*)h;
        float4 x = hf4[2 * i];
        float4 y = hf4[2 * i + 1];
        uint4 o;
        o.x = h2u(__float22half2_rn(make_float2(x.x, x.y)));
        o.y = h2u(__float22half2_rn(make_float2(x.z, x.w)));
        o.z = h2u(__float22half2_rn(make_float2(y.x, y.y)));
        o.w = h2u(__float22half2_rn(make_float2(y.z, y.w)));
        h16[i] = o;
        return;
    }
    // ---------- bucket: 4 edges per thread, independent atomic chains ----------
    int t = blockIdx.x * blockDim.x + threadIdx.x;
    int base = t * 4;
    if (base >= E) return;
    bool m1 = (*mode == 1);
    if (base + 3 < E) {
        int4   s4 = ((const int4*)src)[t];
        int4   d4 = ((const int4*)dst)[t];
        float4 w4 = ((const float4*)w)[t];
        if (!m1) {
            atomicAdd(&deg[s4.x], 1.0f); atomicAdd(&deg[s4.y], 1.0f);
            atomicAdd(&deg[s4.z], 1.0f); atomicAdd(&deg[s4.w], 1.0f);
        }
        int p0 = atomicAdd(&cursor[d4.x], 1);
        int p1 = atomicAdd(&cursor[d4.y], 1);
        int p2 = atomicAdd(&cursor[d4.z], 1);
        int p3 = atomicAdd(&cursor[d4.w], 1);
        unsigned r0 = ((unsigned)s4.x << 16) | wq16(w4.x);
        unsigned r1 = ((unsigned)s4.y << 16) | wq16(w4.y);
        unsigned r2 = ((unsigned)s4.z << 16) | wq16(w4.z);
        unsigned r3 = ((unsigned)s4.w << 16) | wq16(w4.w);
        if (p0 < cap) rec[(size_t)d4.x * cap + p0] = r0; else ovf[atomicAdd(ovfcnt, 1)] = base + 0;
        if (p1 < cap) rec[(size_t)d4.y * cap + p1] = r1; else ovf[atomicAdd(ovfcnt, 1)] = base + 1;
        if (p2 < cap) rec[(size_t)d4.z * cap + p2] = r2; else ovf[atomicAdd(ovfcnt, 1)] = base + 2;
        if (p3 < cap) rec[(size_t)d4.w * cap + p3] = r3; else ovf[atomicAdd(ovfcnt, 1)] = base + 3;
    } else {
        for (int e = base; e < E; ++e) {
            int s = src[e], d = dst[e];
            if (!m1) atomicAdd(&deg[s], 1.0f);
            int pos = atomicAdd(&cursor[d], 1);
            if (pos < cap) rec[(size_t)d * cap + pos] = ((unsigned)s << 16) | wq16(w[e]);
            else ovf[atomicAdd(ovfcnt, 1)] = e;
        }
    }
}

// broadcast record j (group-uniform) to all 32 lanes of the node-group
__device__ __forceinline__ unsigned bcast_rec(unsigned r0, unsigned r1, int j) {
    unsigned lo = __shfl(r0, j & 31, 32);
    unsigned hi = __shfl(r1, j & 31, 32);
    return (j < 32) ? lo : hi;
}

// 32 lanes per dst node; lane owns 4 feats (8B fp16 slice of the 256B row).
__global__ void gather4_f16_kernel(const uint2* __restrict__ h16,
                                   const float* __restrict__ hf,
                                   const int* __restrict__ cursor, const float* __restrict__ deg,
                                   const unsigned* __restrict__ rec, int cap,
                                   const int* __restrict__ ovfcnt, const int* __restrict__ ovf,
                                   const int* __restrict__ src, const int* __restrict__ dst,
                                   const float* __restrict__ w,
                                   float* __restrict__ out, int N, const int* __restrict__ mode) {
    long long gid = (long long)blockIdx.x * blockDim.x + threadIdx.x;
    int node = (int)(gid >> 5);
    int lane = (int)(gid & 31);
    if (node >= N) return;
    bool m1 = (*mode == 1);
    int cnt = cursor[node];
    int inb = cnt < cap ? cnt : cap;
    const unsigned* row = rec + (size_t)node * cap;
    unsigned r0 = (lane < inb) ? row[lane] : 0u;
    unsigned r1 = (lane + 32 < inb) ? row[lane + 32] : 0u;

    float a0 = 0.f, a1 = 0.f, a2 = 0.f, a3 = 0.f;
    float b0 = 0.f, b1 = 0.f, b2 = 0.f, b3 = 0.f;
    float c0 = 0.f, c1 = 0.f, c2 = 0.f, c3 = 0.f;
    float d0 = 0.f, d1 = 0.f, d2 = 0.f, d3 = 0.f;

    int j = 0;
    if (m1) {
        const float Q = 1.52587890625e-05f;  // 2^-16
        for (; j + 3 < inb; j += 4) {
            unsigned m0 = bcast_rec(r0, r1, j);
            unsigned m1r = bcast_rec(r0, r1, j + 1);
            unsigned m2r = bcast_rec(r0, r1, j + 2);
            unsigned m3r = bcast_rec(r0, r1, j + 3);
            float sc0 = ((float)(m0 & 0xFFFFu) + 0.5f) * Q;
            float sc1 = ((float)(m1r & 0xFFFFu) + 0.5f) * Q;
            float sc2 = ((float)(m2r & 0xFFFFu) + 0.5f) * Q;
            float sc3 = ((float)(m3r & 0xFFFFu) + 0.5f) * Q;
            uint2 v0 = h16[(size_t)(m0 >> 16) * 32 + lane];
            uint2 v1 = h16[(size_t)(m1r >> 16) * 32 + lane];
            uint2 v2 = h16[(size_t)(m2r >> 16) * 32 + lane];
            uint2 v3 = h16[(size_t)(m3r >> 16) * 32 + lane];
            float2 f0a = u2f2(v0.x), f0b = u2f2(v0.y);
            float2 f1a = u2f2(v1.x), f1b = u2f2(v1.y);
            float2 f2a = u2f2(v2.x), f2b = u2f2(v2.y);
            float2 f3a = u2f2(v3.x), f3b = u2f2(v3.y);
            a0 += f0a.x * sc0; a1 += f0a.y * sc0; a2 += f0b.x * sc0; a3 += f0b.y * sc0;
            b0 += f1a.x * sc1; b1 += f1a.y * sc1; b2 += f1b.x * sc1; b3 += f1b.y * sc1;
            c0 += f2a.x * sc2; c1 += f2a.y * sc2; c2 += f2b.x * sc2; c3 += f2b.y * sc2;
            d0 += f3a.x * sc3; d1 += f3a.y * sc3; d2 += f3b.x * sc3; d3 += f3b.y * sc3;
        }
        for (; j < inb; ++j) {
            unsigned m0 = bcast_rec(r0, r1, j);
            float sc0 = ((float)(m0 & 0xFFFFu) + 0.5f) * Q;
            uint2 v0 = h16[(size_t)(m0 >> 16) * 32 + lane];
            float2 f0a = u2f2(v0.x), f0b = u2f2(v0.y);
            a0 += f0a.x * sc0; a1 += f0a.y * sc0; a2 += f0b.x * sc0; a3 += f0b.y * sc0;
        }
    } else {
        for (; j + 3 < inb; j += 4) {
            unsigned m0 = bcast_rec(r0, r1, j);
            unsigned m1r = bcast_rec(r0, r1, j + 1);
            unsigned m2r = bcast_rec(r0, r1, j + 2);
            unsigned m3r = bcast_rec(r0, r1, j + 3);
            int s0 = (int)(m0 >> 16), s1 = (int)(m1r >> 16);
            int s2 = (int)(m2r >> 16), s3 = (int)(m3r >> 16);
            float sc0 = rsqrtf(deg[s0]);
            float sc1 = rsqrtf(deg[s1]);
            float sc2 = rsqrtf(deg[s2]);
            float sc3 = rsqrtf(deg[s3]);
            uint2 v0 = h16[(size_t)s0 * 32 + lane];
            uint2 v1 = h16[(size_t)s1 * 32 + lane];
            uint2 v2 = h16[(size_t)s2 * 32 + lane];
            uint2 v3 = h16[(size_t)s3 * 32 + lane];
            float2 f0a = u2f2(v0.x), f0b = u2f2(v0.y);
            float2 f1a = u2f2(v1.x), f1b = u2f2(v1.y);
            float2 f2a = u2f2(v2.x), f2b = u2f2(v2.y);
            float2 f3a = u2f2(v3.x), f3b = u2f2(v3.y);
            a0 += f0a.x * sc0; a1 += f0a.y * sc0; a2 += f0b.x * sc0; a3 += f0b.y * sc0;
            b0 += f1a.x * sc1; b1 += f1a.y * sc1; b2 += f1b.x * sc1; b3 += f1b.y * sc1;
            c0 += f2a.x * sc2; c1 += f2a.y * sc2; c2 += f2b.x * sc2; c3 += f2b.y * sc2;
            d0 += f3a.x * sc3; d1 += f3a.y * sc3; d2 += f3b.x * sc3; d3 += f3b.y * sc3;
        }
        for (; j < inb; ++j) {
            unsigned m0 = bcast_rec(r0, r1, j);
            int s0 = (int)(m0 >> 16);
            float sc0 = rsqrtf(deg[s0]);
            uint2 v0 = h16[(size_t)s0 * 32 + lane];
            float2 f0a = u2f2(v0.x), f0b = u2f2(v0.y);
            a0 += f0a.x * sc0; a1 += f0a.y * sc0; a2 += f0b.x * sc0; a3 += f0b.y * sc0;
        }
    }

    a0 += b0 + c0 + d0; a1 += b1 + c1 + d1;
    a2 += b2 + c2 + d2; a3 += b3 + c3 + d3;

    if (cnt > cap) {                                  // exact overflow path (~never taken)
        int total = *ovfcnt;
        for (int k = 0; k < total; ++k) {
            int e = ovf[k];
            if (dst[e] == node) {
                int s = src[e];
                float sc = m1 ? w[e] : rsqrtf(deg[s]);
                float4 v = ((const float4*)(hf + (long long)s * D_FEAT))[lane];
                a0 += v.x * sc; a1 += v.y * sc; a2 += v.z * sc; a3 += v.w * sc;
            }
        }
    }
    float fin = m1 ? 1.0f : rsqrtf(deg[node]);        // deg==0 -> inf, matches powf(0,-0.5)
    float4 r; r.x = a0 * fin; r.y = a1 * fin; r.z = a2 * fin; r.w = a3 * fin;
    ((float4*)(out + (long long)node * D_FEAT))[lane] = r;
}

// ================= f32 fallback path (no ws room for h16) =================

__global__ void bucket_multi_kernel(const int* __restrict__ src, const int* __restrict__ dst,
                                    const float* __restrict__ w,
                                    int* __restrict__ cursor, float* __restrict__ deg,
                                    int* __restrict__ ovfcnt, int* __restrict__ ovf,
                                    unsigned* __restrict__ rec, int cap,
                                    int E, const int* __restrict__ mode) {
    int t = blockIdx.x * blockDim.x + threadIdx.x;
    int base = t * 4;
    if (base >= E) return;
    bool m1 = (*mode == 1);
    if (base + 3 < E) {
        int4   s4 = ((const int4*)src)[t];
        int4   d4 = ((const int4*)dst)[t];
        float4 w4 = ((const float4*)w)[t];
        if (!m1) {
            atomicAdd(&deg[s4.x], 1.0f); atomicAdd(&deg[s4.y], 1.0f);
            atomicAdd(&deg[s4.z], 1.0f); atomicAdd(&deg[s4.w], 1.0f);
        }
        int p0 = atomicAdd(&cursor[d4.x], 1);
        int p1 = atomicAdd(&cursor[d4.y], 1);
        int p2 = atomicAdd(&cursor[d4.z], 1);
        int p3 = atomicAdd(&cursor[d4.w], 1);
        unsigned r0 = ((unsigned)s4.x << 16) | wq16(w4.x);
        unsigned r1 = ((unsigned)s4.y << 16) | wq16(w4.y);
        unsigned r2 = ((unsigned)s4.z << 16) | wq16(w4.z);
        unsigned r3 = ((unsigned)s4.w << 16) | wq16(w4.w);
        if (p0 < cap) rec[(size_t)d4.x * cap + p0] = r0; else ovf[atomicAdd(ovfcnt, 1)] = base + 0;
        if (p1 < cap) rec[(size_t)d4.y * cap + p1] = r1; else ovf[atomicAdd(ovfcnt, 1)] = base + 1;
        if (p2 < cap) rec[(size_t)d4.z * cap + p2] = r2; else ovf[atomicAdd(ovfcnt, 1)] = base + 2;
        if (p3 < cap) rec[(size_t)d4.w * cap + p3] = r3; else ovf[atomicAdd(ovfcnt, 1)] = base + 3;
    } else {
        for (int e = base; e < E; ++e) {
            int s = src[e], d = dst[e];
            if (!m1) atomicAdd(&deg[s], 1.0f);
            int pos = atomicAdd(&cursor[d], 1);
            if (pos < cap) rec[(size_t)d * cap + pos] = ((unsigned)s << 16) | wq16(w[e]);
            else ovf[atomicAdd(ovfcnt, 1)] = e;
        }
    }
}

__global__ void gather4_f32_kernel(const float* __restrict__ h,
                                   const int* __restrict__ cursor, const float* __restrict__ deg,
                                   const unsigned* __restrict__ rec, int cap,
                                   const int* __restrict__ ovfcnt, const int* __restrict__ ovf,
                                   const int* __restrict__ src, const int* __restrict__ dst,
                                   const float* __restrict__ w,
                                   float* __restrict__ out, int N, const int* __restrict__ mode) {
    long long gid = (long long)blockIdx.x * blockDim.x + threadIdx.x;
    int node = (int)(gid >> 5);
    int lane = (int)(gid & 31);
    if (node >= N) return;
    bool m1 = (*mode == 1);
    int cnt = cursor[node];
    int inb = cnt < cap ? cnt : cap;
    const unsigned* row = rec + (size_t)node * cap;
    unsigned r0 = (lane < inb) ? row[lane] : 0u;
    unsigned r1 = (lane + 32 < inb) ? row[lane + 32] : 0u;
    const float4* h4 = (const float4*)h;
    float a0 = 0.f, a1 = 0.f, a2 = 0.f, a3 = 0.f;
    float b0 = 0.f, b1 = 0.f, b2 = 0.f, b3 = 0.f;
    int j = 0;
    const float Q = 1.52587890625e-05f;
    for (; j + 1 < inb; j += 2) {
        unsigned m0 = bcast_rec(r0, r1, j);
        unsigned m1r = bcast_rec(r0, r1, j + 1);
        int s0 = (int)(m0 >> 16), s1 = (int)(m1r >> 16);
        float sc0 = m1 ? ((float)(m0 & 0xFFFFu) + 0.5f) * Q : rsqrtf(deg[s0]);
        float sc1 = m1 ? ((float)(m1r & 0xFFFFu) + 0.5f) * Q : rsqrtf(deg[s1]);
        float4 v0 = h4[(size_t)s0 * 32 + lane];
        float4 v1 = h4[(size_t)s1 * 32 + lane];
        a0 += v0.x * sc0; a1 += v0.y * sc0; a2 += v0.z * sc0; a3 += v0.w * sc0;
        b0 += v1.x * sc1; b1 += v1.y * sc1; b2 += v1.z * sc1; b3 += v1.w * sc1;
    }
    if (j < inb) {
        unsigned m0 = bcast_rec(r0, r1, j);
        int s0 = (int)(m0 >> 16);
        float sc0 = m1 ? ((float)(m0 & 0xFFFFu) + 0.5f) * Q : rsqrtf(deg[s0]);
        float4 v0 = h4[(size_t)s0 * 32 + lane];
        a0 += v0.x * sc0; a1 += v0.y * sc0; a2 += v0.z * sc0; a3 += v0.w * sc0;
    }
    a0 += b0; a1 += b1; a2 += b2; a3 += b3;
    if (cnt > cap) {
        int total = *ovfcnt;
        for (int k = 0; k < total; ++k) {
            int e = ovf[k];
            if (dst[e] == node) {
                int s = src[e];
                float sc = m1 ? w[e] : rsqrtf(deg[s]);
                float4 v = ((const float4*)(h + (long long)s * D_FEAT))[lane];
                a0 += v.x * sc; a1 += v.y * sc; a2 += v.z * sc; a3 += v.w * sc;
            }
        }
    }
    float fin = m1 ? 1.0f : rsqrtf(deg[node]);
    float4 r; r.x = a0 * fin; r.y = a1 * fin; r.z = a2 * fin; r.w = a3 * fin;
    ((float4*)(out + (long long)node * D_FEAT))[lane] = r;
}

// ================= PATH C: 8B records (smaller ws) =================

__global__ void bucket_direct_kernel(const int* __restrict__ src, const int* __restrict__ dst,
                                     const float* __restrict__ w,
                                     int* __restrict__ cursor, float* __restrict__ deg,
                                     int* __restrict__ ovfcnt, int* __restrict__ ovf,
                                     uint2* __restrict__ epack, int cap,
                                     int E, const int* __restrict__ mode) {
    int e = blockIdx.x * blockDim.x + threadIdx.x;
    if (e >= E) return;
    bool m1 = (*mode == 1);
    int d = dst[e];
    int s = src[e];
    if (!m1) atomicAdd(&deg[s], 1.0f);
    int pos = atomicAdd(&cursor[d], 1);
    if (pos < cap) {
        float sc = m1 ? w[e] : 0.0f;
        epack[(size_t)d * cap + pos] = make_uint2((unsigned)s, __float_as_uint(sc));
    } else {
        ovf[atomicAdd(ovfcnt, 1)] = e;
    }
}

__global__ void gather_cap_kernel(const float* __restrict__ h,
                                  const int* __restrict__ cursor, const float* __restrict__ deg,
                                  const uint2* __restrict__ epack, int cap,
                                  const int* __restrict__ ovfcnt, const int* __restrict__ ovf,
                                  const int* __restrict__ src, const int* __restrict__ dst,
                                  const float* __restrict__ w,
                                  float* __restrict__ out, int N, const int* __restrict__ mode) {
    long long gid = (long long)blockIdx.x * blockDim.x + threadIdx.x;
    int node = (int)(gid >> 5);
    int lane = (int)(gid & 31);
    if (node >= N) return;
    bool m1 = (*mode == 1);
    int cnt = cursor[node];
    int inb = cnt < cap ? cnt : cap;
    const uint2* row = epack + (size_t)node * cap;
    float a0 = 0.f, a1 = 0.f, a2 = 0.f, a3 = 0.f;
    for (int j = 0; j < inb; ++j) {
        uint2 m = row[j];
        int s = (int)m.x;
        float sc = m1 ? __uint_as_float(m.y) : rsqrtf(deg[s]);
        float4 v = ((const float4*)(h + (long long)s * D_FEAT))[lane];
        a0 += v.x * sc; a1 += v.y * sc; a2 += v.z * sc; a3 += v.w * sc;
    }
    if (cnt > cap) {
        int total = *ovfcnt;
        for (int k = 0; k < total; ++k) {
            int e = ovf[k];
            if (dst[e] == node) {
                int s = src[e];
                float sc = m1 ? w[e] : rsqrtf(deg[s]);
                float4 v = ((const float4*)(h + (long long)s * D_FEAT))[lane];
                a0 += v.x * sc; a1 += v.y * sc; a2 += v.z * sc; a3 += v.w * sc;
            }
        }
    }
    float fin = m1 ? 1.0f : rsqrtf(deg[node]);
    float4 r; r.x = a0 * fin; r.y = a1 * fin; r.z = a2 * fin; r.w = a3 * fin;
    ((float4*)(out + (long long)node * D_FEAT))[lane] = r;
}

// ================= ultra-fallback: atomic scatter =================

__global__ void fb_deg_kernel(const int* __restrict__ src, float* __restrict__ deg,
                              int E, const int* __restrict__ mode) {
    if (*mode == 1) return;
    int e = blockIdx.x * blockDim.x + threadIdx.x;
    if (e < E) atomicAdd(&deg[src[e]], 1.0f);
}
__global__ void fb_norm_kernel(const float* __restrict__ deg, float* __restrict__ norm,
                               int N, const int* __restrict__ mode) {
    if (*mode == 1) return;
    int i = blockIdx.x * blockDim.x + threadIdx.x;
    if (i < N) norm[i] = rsqrtf(deg[i]);
}
__global__ void fb_scatter_kernel(const float* __restrict__ h, const float* __restrict__ w,
                                  const int* __restrict__ src, const int* __restrict__ dst,
                                  const float* __restrict__ norm, float* __restrict__ out,
                                  int E, const int* __restrict__ mode) {
    long long gid = (long long)blockIdx.x * blockDim.x + threadIdx.x;
    int e = (int)(gid >> 5);
    int lane = (int)(gid & 31);
    if (e >= E) return;
    int s = src[e], d = dst[e];
    float scale = (*mode == 1) ? w[e] : norm[s];
    float4 v = ((const float4*)(h + (long long)s * D_FEAT))[lane];
    float* op = out + (long long)d * D_FEAT + lane * 4;
    atomicAdd(op + 0, v.x * scale);
    atomicAdd(op + 1, v.y * scale);
    atomicAdd(op + 2, v.z * scale);
    atomicAdd(op + 3, v.w * scale);
}
__global__ void fb_scale_kernel(float* __restrict__ out, const float* __restrict__ norm,
                                int N, const int* __restrict__ mode) {
    if (*mode == 1) return;
    int idx = blockIdx.x * blockDim.x + threadIdx.x;
    int total = N * (D_FEAT / 4);
    if (idx >= total) return;
    int node = idx / (D_FEAT / 4);
    float4* op = (float4*)out + idx;
    float4 v = *op;
    float nn = norm[node];
    v.x *= nn; v.y *= nn; v.z *= nn; v.w *= nn;
    *op = v;
}

// ================= host =================

extern "C" void kernel_launch(void* const* d_in, const int* in_sizes, int n_in,
                              void* d_out, int out_size, void* d_ws, size_t ws_size,
                              hipStream_t stream) {
    const float* h    = (const float*)d_in[0];
    const float* w    = (const float*)d_in[1];
    const int*   src  = (const int*)d_in[2];
    const int*   dst  = (const int*)d_in[3];
    const int*   mode = (const int*)d_in[4];

    int ND = in_sizes[0];
    int E  = in_sizes[1];
    int N  = ND / D_FEAT;

    float* out = (float*)d_out;

    size_t ws_words    = ws_size / 4;
    size_t fixed_words = 2 * (size_t)N + 1 + (size_t)E;   // cursor, deg, ovfcnt, ovf

    int*   cursor = (int*)d_ws;
    float* deg    = (float*)(cursor + N);
    int*   ovfcnt = (int*)(deg + N);
    int*   ovf    = ovfcnt + 1;

    // ---------- fp16 path: h16 cache + 4B records ----------
    size_t h16_off   = (fixed_words + 3) & ~(size_t)3;        // 16B align
    size_t h16_words = (size_t)N * (D_FEAT / 2);              // N*128 halfs
    size_t rec16_off = h16_off + h16_words;
    long capH = 0;
    if (ws_words > rec16_off) capH = (long)((ws_words - rec16_off) / (size_t)N);
    if (capH > 64) capH = 64;

    if (N <= 65536 && capH >= 28) {
        uint4*    h16 = (uint4*)((int*)d_ws + h16_off);
        unsigned* rec = (unsigned*)((int*)d_ws + rec16_off);
        int cap = (int)capH;

        hipMemsetAsync(d_ws, 0, (2 * (size_t)N + 1) * sizeof(int), stream);

        int nGroups8     = ND / 8;                            // 8 floats per convert thread
        int nBucketBlks  = ((E + 3) / 4 + 255) / 256;
        int nConvBlks    = (nGroups8 + 255) / 256;
        bucket_conv_kernel<<<nBucketBlks + nConvBlks, 256, 0, stream>>>(
            h, src, dst, w, cursor, deg, ovfcnt, ovf, rec, cap, h16,
            E, nBucketBlks, nGroups8, mode);

        long long gt = (long long)N * 32;
        gather4_f16_kernel<<<(int)((gt + 255) / 256), 256, 0, stream>>>(
            (const uint2*)h16, h, cursor, deg, rec, cap, ovfcnt, ovf, src, dst, w,
            out, N, mode);
        return;
    }

    // ---------- f32 path: 4B records, no h16 ----------
    size_t rec_off = fixed_words;
    long capA = 0;
    if (ws_words > rec_off) capA = (long)((ws_words - rec_off) / (size_t)N);
    if (capA > 64) capA = 64;

    if (N <= 65536 && capA >= 28) {
        unsigned* rec = (unsigned*)((int*)d_ws + rec_off);
        int cap = (int)capA;
        hipMemsetAsync(d_ws, 0, (2 * (size_t)N + 1) * sizeof(int), stream);
        int nthreads = (E + 3) / 4;
        bucket_multi_kernel<<<(nthreads + 255) / 256, 256, 0, stream>>>(
            src, dst, w, cursor, deg, ovfcnt, ovf, rec, cap, E, mode);
        long long gt = (long long)N * 32;
        gather4_f32_kernel<<<(int)((gt + 255) / 256), 256, 0, stream>>>(
            h, cursor, deg, rec, cap, ovfcnt, ovf, src, dst, w, out, N, mode);
        return;
    }

    // ---------- PATH C: 8B records ----------
    size_t epack_off = (fixed_words + 1) & ~(size_t)1;
    long capC = 0;
    if (ws_words > epack_off) capC = (long)((ws_words - epack_off) / (2 * (size_t)N));
    if (capC > 64) capC = 64;

    if (capC >= 8) {
        uint2* epack = (uint2*)((int*)d_ws + epack_off);
        hipMemsetAsync(d_ws, 0, (2 * (size_t)N + 1) * sizeof(int), stream);
        bucket_direct_kernel<<<(E + 255) / 256, 256, 0, stream>>>(
            src, dst, w, cursor, deg, ovfcnt, ovf, epack, (int)capC, E, mode);
        long long gt = (long long)N * 32;
        gather_cap_kernel<<<(int)((gt + 255) / 256), 256, 0, stream>>>(
            h, cursor, deg, epack, (int)capC, ovfcnt, ovf, src, dst, w, out, N, mode);
        return;
    }

    // ---------- ultra-fallback: atomic scatter ----------
    float* degF  = (float*)d_ws;
    float* normF = degF + N;
    hipMemsetAsync(d_out, 0, (size_t)out_size * sizeof(float), stream);
    hipMemsetAsync(d_ws, 0, (size_t)N * sizeof(float), stream);
    fb_deg_kernel<<<(E + 255) / 256, 256, 0, stream>>>(src, degF, E, mode);
    fb_norm_kernel<<<(N + 255) / 256, 256, 0, stream>>>(degF, normF, N, mode);
    long long tt = (long long)E * 32;
    fb_scatter_kernel<<<(int)((tt + 255) / 256), 256, 0, stream>>>(h, w, src, dst,
                                                                   normF, out, E, mode);
    int st = N * (D_FEAT / 4);
    fb_scale_kernel<<<(st + 255) / 256, 256, 0, stream>>>(out, normF, N, mode);
}

// Round 4
// 152.992 us; speedup vs baseline: 1.0417x; 1.0025x over previous
//
#include <hip/hip_runtime.h>
#include <hip/hip_fp16.h>

#define D_FEAT 128

// ================= fixed-capacity bucketing + fp16 feature cache =================
//
// ws layout, fp16 path (words):
//   cursor[N*cs] | deg[N] | ovfcnt[1] | ovf[E] | pad->16B | h16[N*64] | rec[N*cap]
// cs = cursor stride (16 -> one counter per 64B line: avoids line-level atomic
// serialization; ~200 atomics/line at cs=1 with 12.5 edges/node avg).
// record = {src:16, w_q:16}; w in [0,1) -> 16-bit midpoint quant (err <= 2^-17).
// h cached as fp16 rows (256B): halves gather HBM bytes (~5e-3 absmax vs 0.0625 tol).

__device__ __forceinline__ unsigned wq16(float f) {
    int q = (int)(f * 65536.0f);
    if (q < 0) q = 0;
    if (q > 65535) q = 65535;
    return (unsigned)q;
}

__device__ __forceinline__ unsigned h2u(__half2 v) {
    union { __half2 h; unsigned u; } cv; cv.h = v; return cv.u;
}
__device__ __forceinline__ float2 u2f2(unsigned u) {
    union { unsigned u; __half2 h; } cv; cv.u = u;
    return __half22float2(cv.h);
}

// ---- fused: [0, nBucketBlocks) buckets edges (1 edge/thread -> max waves);
//      remaining blocks convert h -> fp16 ----
__global__ void bucket_conv_kernel(const float* __restrict__ h,
                                   const int* __restrict__ src, const int* __restrict__ dst,
                                   const float* __restrict__ w,
                                   int* __restrict__ cursor, float* __restrict__ deg,
                                   int* __restrict__ ovfcnt, int* __restrict__ ovf,
                                   unsigned* __restrict__ rec, int cap,
                                   uint4* __restrict__ h16,
                                   int E, int nBucketBlocks, int nGroups8, int cs,
                                   const int* __restrict__ mode) {
    if ((int)blockIdx.x >= nBucketBlocks) {
        // ---------- convert: 8 floats -> 8 halfs per thread ----------
        int i = (blockIdx.x - nBucketBlocks) * blockDim.x + threadIdx.x;
        if (i >= nGroups8) return;
        const float4* hf4 = (const float4*)h;
        float4 x = hf4[2 * i];
        float4 y = hf4[2 * i + 1];
        uint4 o;
        o.x = h2u(__float22half2_rn(make_float2(x.x, x.y)));
        o.y = h2u(__float22half2_rn(make_float2(x.z, x.w)));
        o.z = h2u(__float22half2_rn(make_float2(y.x, y.y)));
        o.w = h2u(__float22half2_rn(make_float2(y.z, y.w)));
        h16[i] = o;
        return;
    }
    // ---------- bucket: 1 edge/thread ----------
    int e = blockIdx.x * blockDim.x + threadIdx.x;
    if (e >= E) return;
    bool m1 = (*mode == 1);
    int s = src[e];
    int d = dst[e];
    float wv = w[e];
    if (!m1) atomicAdd(&deg[s], 1.0f);
    int pos = atomicAdd(&cursor[(size_t)d * cs], 1);
    unsigned r = ((unsigned)s << 16) | wq16(wv);
    if (pos < cap) rec[(size_t)d * cap + pos] = r;
    else           ovf[atomicAdd(ovfcnt, 1)] = e;
}

// broadcast record j (group-uniform) to all 32 lanes of the node-group
__device__ __forceinline__ unsigned bcast_rec(unsigned r0, unsigned r1, int j) {
    unsigned lo = __shfl(r0, j & 31, 32);
    unsigned hi = __shfl(r1, j & 31, 32);
    return (j < 32) ? lo : hi;
}

// 32 lanes per dst node; lane owns 4 feats (8B fp16 slice of the 256B row).
__global__ void gather4_f16_kernel(const uint2* __restrict__ h16,
                                   const float* __restrict__ hf,
                                   const int* __restrict__ cursor, const float* __restrict__ deg,
                                   const unsigned* __restrict__ rec, int cap,
                                   const int* __restrict__ ovfcnt, const int* __restrict__ ovf,
                                   const int* __restrict__ src, const int* __restrict__ dst,
                                   const float* __restrict__ w,
                                   float* __restrict__ out, int N, int cs,
                                   const int* __restrict__ mode) {
    long long gid = (long long)blockIdx.x * blockDim.x + threadIdx.x;
    int node = (int)(gid >> 5);
    int lane = (int)(gid & 31);
    if (node >= N) return;
    bool m1 = (*mode == 1);
    int cnt = cursor[(size_t)node * cs];
    int inb = cnt < cap ? cnt : cap;
    const unsigned* row = rec + (size_t)node * cap;
    unsigned r0 = (lane < inb) ? row[lane] : 0u;
    unsigned r1 = (lane + 32 < inb) ? row[lane + 32] : 0u;

    float a0 = 0.f, a1 = 0.f, a2 = 0.f, a3 = 0.f;
    float b0 = 0.f, b1 = 0.f, b2 = 0.f, b3 = 0.f;
    float c0 = 0.f, c1 = 0.f, c2 = 0.f, c3 = 0.f;
    float d0 = 0.f, d1 = 0.f, d2 = 0.f, d3 = 0.f;

    int j = 0;
    if (m1) {
        const float Q = 1.52587890625e-05f;  // 2^-16
        for (; j + 3 < inb; j += 4) {
            unsigned m0 = bcast_rec(r0, r1, j);
            unsigned m1r = bcast_rec(r0, r1, j + 1);
            unsigned m2r = bcast_rec(r0, r1, j + 2);
            unsigned m3r = bcast_rec(r0, r1, j + 3);
            float sc0 = ((float)(m0 & 0xFFFFu) + 0.5f) * Q;
            float sc1 = ((float)(m1r & 0xFFFFu) + 0.5f) * Q;
            float sc2 = ((float)(m2r & 0xFFFFu) + 0.5f) * Q;
            float sc3 = ((float)(m3r & 0xFFFFu) + 0.5f) * Q;
            uint2 v0 = h16[(size_t)(m0 >> 16) * 32 + lane];
            uint2 v1 = h16[(size_t)(m1r >> 16) * 32 + lane];
            uint2 v2 = h16[(size_t)(m2r >> 16) * 32 + lane];
            uint2 v3 = h16[(size_t)(m3r >> 16) * 32 + lane];
            float2 f0a = u2f2(v0.x), f0b = u2f2(v0.y);
            float2 f1a = u2f2(v1.x), f1b = u2f2(v1.y);
            float2 f2a = u2f2(v2.x), f2b = u2f2(v2.y);
            float2 f3a = u2f2(v3.x), f3b = u2f2(v3.y);
            a0 += f0a.x * sc0; a1 += f0a.y * sc0; a2 += f0b.x * sc0; a3 += f0b.y * sc0;
            b0 += f1a.x * sc1; b1 += f1a.y * sc1; b2 += f1b.x * sc1; b3 += f1b.y * sc1;
            c0 += f2a.x * sc2; c1 += f2a.y * sc2; c2 += f2b.x * sc2; c3 += f2b.y * sc2;
            d0 += f3a.x * sc3; d1 += f3a.y * sc3; d2 += f3b.x * sc3; d3 += f3b.y * sc3;
        }
        for (; j < inb; ++j) {
            unsigned m0 = bcast_rec(r0, r1, j);
            float sc0 = ((float)(m0 & 0xFFFFu) + 0.5f) * Q;
            uint2 v0 = h16[(size_t)(m0 >> 16) * 32 + lane];
            float2 f0a = u2f2(v0.x), f0b = u2f2(v0.y);
            a0 += f0a.x * sc0; a1 += f0a.y * sc0; a2 += f0b.x * sc0; a3 += f0b.y * sc0;
        }
    } else {
        for (; j + 3 < inb; j += 4) {
            unsigned m0 = bcast_rec(r0, r1, j);
            unsigned m1r = bcast_rec(r0, r1, j + 1);
            unsigned m2r = bcast_rec(r0, r1, j + 2);
            unsigned m3r = bcast_rec(r0, r1, j + 3);
            int s0 = (int)(m0 >> 16), s1 = (int)(m1r >> 16);
            int s2 = (int)(m2r >> 16), s3 = (int)(m3r >> 16);
            float sc0 = rsqrtf(deg[s0]);
            float sc1 = rsqrtf(deg[s1]);
            float sc2 = rsqrtf(deg[s2]);
            float sc3 = rsqrtf(deg[s3]);
            uint2 v0 = h16[(size_t)s0 * 32 + lane];
            uint2 v1 = h16[(size_t)s1 * 32 + lane];
            uint2 v2 = h16[(size_t)s2 * 32 + lane];
            uint2 v3 = h16[(size_t)s3 * 32 + lane];
            float2 f0a = u2f2(v0.x), f0b = u2f2(v0.y);
            float2 f1a = u2f2(v1.x), f1b = u2f2(v1.y);
            float2 f2a = u2f2(v2.x), f2b = u2f2(v2.y);
            float2 f3a = u2f2(v3.x), f3b = u2f2(v3.y);
            a0 += f0a.x * sc0; a1 += f0a.y * sc0; a2 += f0b.x * sc0; a3 += f0b.y * sc0;
            b0 += f1a.x * sc1; b1 += f1a.y * sc1; b2 += f1b.x * sc1; b3 += f1b.y * sc1;
            c0 += f2a.x * sc2; c1 += f2a.y * sc2; c2 += f2b.x * sc2; c3 += f2b.y * sc2;
            d0 += f3a.x * sc3; d1 += f3a.y * sc3; d2 += f3b.x * sc3; d3 += f3b.y * sc3;
        }
        for (; j < inb; ++j) {
            unsigned m0 = bcast_rec(r0, r1, j);
            int s0 = (int)(m0 >> 16);
            float sc0 = rsqrtf(deg[s0]);
            uint2 v0 = h16[(size_t)s0 * 32 + lane];
            float2 f0a = u2f2(v0.x), f0b = u2f2(v0.y);
            a0 += f0a.x * sc0; a1 += f0a.y * sc0; a2 += f0b.x * sc0; a3 += f0b.y * sc0;
        }
    }

    a0 += b0 + c0 + d0; a1 += b1 + c1 + d1;
    a2 += b2 + c2 + d2; a3 += b3 + c3 + d3;

    if (cnt > cap) {                                  // exact overflow path (~never taken)
        int total = *ovfcnt;
        for (int k = 0; k < total; ++k) {
            int e = ovf[k];
            if (dst[e] == node) {
                int s = src[e];
                float sc = m1 ? w[e] : rsqrtf(deg[s]);
                float4 v = ((const float4*)(hf + (long long)s * D_FEAT))[lane];
                a0 += v.x * sc; a1 += v.y * sc; a2 += v.z * sc; a3 += v.w * sc;
            }
        }
    }
    float fin = m1 ? 1.0f : rsqrtf(deg[node]);        // deg==0 -> inf, matches powf(0,-0.5)
    float4 r; r.x = a0 * fin; r.y = a1 * fin; r.z = a2 * fin; r.w = a3 * fin;
    ((float4*)(out + (long long)node * D_FEAT))[lane] = r;
}

// ================= f32 fallback path (no ws room for h16) =================

__global__ void bucket_multi_kernel(const int* __restrict__ src, const int* __restrict__ dst,
                                    const float* __restrict__ w,
                                    int* __restrict__ cursor, float* __restrict__ deg,
                                    int* __restrict__ ovfcnt, int* __restrict__ ovf,
                                    unsigned* __restrict__ rec, int cap,
                                    int E, const int* __restrict__ mode) {
    int t = blockIdx.x * blockDim.x + threadIdx.x;
    int base = t * 4;
    if (base >= E) return;
    bool m1 = (*mode == 1);
    if (base + 3 < E) {
        int4   s4 = ((const int4*)src)[t];
        int4   d4 = ((const int4*)dst)[t];
        float4 w4 = ((const float4*)w)[t];
        if (!m1) {
            atomicAdd(&deg[s4.x], 1.0f); atomicAdd(&deg[s4.y], 1.0f);
            atomicAdd(&deg[s4.z], 1.0f); atomicAdd(&deg[s4.w], 1.0f);
        }
        int p0 = atomicAdd(&cursor[d4.x], 1);
        int p1 = atomicAdd(&cursor[d4.y], 1);
        int p2 = atomicAdd(&cursor[d4.z], 1);
        int p3 = atomicAdd(&cursor[d4.w], 1);
        unsigned r0 = ((unsigned)s4.x << 16) | wq16(w4.x);
        unsigned r1 = ((unsigned)s4.y << 16) | wq16(w4.y);
        unsigned r2 = ((unsigned)s4.z << 16) | wq16(w4.z);
        unsigned r3 = ((unsigned)s4.w << 16) | wq16(w4.w);
        if (p0 < cap) rec[(size_t)d4.x * cap + p0] = r0; else ovf[atomicAdd(ovfcnt, 1)] = base + 0;
        if (p1 < cap) rec[(size_t)d4.y * cap + p1] = r1; else ovf[atomicAdd(ovfcnt, 1)] = base + 1;
        if (p2 < cap) rec[(size_t)d4.z * cap + p2] = r2; else ovf[atomicAdd(ovfcnt, 1)] = base + 2;
        if (p3 < cap) rec[(size_t)d4.w * cap + p3] = r3; else ovf[atomicAdd(ovfcnt, 1)] = base + 3;
    } else {
        for (int e = base; e < E; ++e) {
            int s = src[e], d = dst[e];
            if (!m1) atomicAdd(&deg[s], 1.0f);
            int pos = atomicAdd(&cursor[d], 1);
            if (pos < cap) rec[(size_t)d * cap + pos] = ((unsigned)s << 16) | wq16(w[e]);
            else ovf[atomicAdd(ovfcnt, 1)] = e;
        }
    }
}

__global__ void gather4_f32_kernel(const float* __restrict__ h,
                                   const int* __restrict__ cursor, const float* __restrict__ deg,
                                   const unsigned* __restrict__ rec, int cap,
                                   const int* __restrict__ ovfcnt, const int* __restrict__ ovf,
                                   const int* __restrict__ src, const int* __restrict__ dst,
                                   const float* __restrict__ w,
                                   float* __restrict__ out, int N, const int* __restrict__ mode) {
    long long gid = (long long)blockIdx.x * blockDim.x + threadIdx.x;
    int node = (int)(gid >> 5);
    int lane = (int)(gid & 31);
    if (node >= N) return;
    bool m1 = (*mode == 1);
    int cnt = cursor[node];
    int inb = cnt < cap ? cnt : cap;
    const unsigned* row = rec + (size_t)node * cap;
    unsigned r0 = (lane < inb) ? row[lane] : 0u;
    unsigned r1 = (lane + 32 < inb) ? row[lane + 32] : 0u;
    const float4* h4 = (const float4*)h;
    float a0 = 0.f, a1 = 0.f, a2 = 0.f, a3 = 0.f;
    float b0 = 0.f, b1 = 0.f, b2 = 0.f, b3 = 0.f;
    int j = 0;
    const float Q = 1.52587890625e-05f;
    for (; j + 1 < inb; j += 2) {
        unsigned m0 = bcast_rec(r0, r1, j);
        unsigned m1r = bcast_rec(r0, r1, j + 1);
        int s0 = (int)(m0 >> 16), s1 = (int)(m1r >> 16);
        float sc0 = m1 ? ((float)(m0 & 0xFFFFu) + 0.5f) * Q : rsqrtf(deg[s0]);
        float sc1 = m1 ? ((float)(m1r & 0xFFFFu) + 0.5f) * Q : rsqrtf(deg[s1]);
        float4 v0 = h4[(size_t)s0 * 32 + lane];
        float4 v1 = h4[(size_t)s1 * 32 + lane];
        a0 += v0.x * sc0; a1 += v0.y * sc0; a2 += v0.z * sc0; a3 += v0.w * sc0;
        b0 += v1.x * sc1; b1 += v1.y * sc1; b2 += v1.z * sc1; b3 += v1.w * sc1;
    }
    if (j < inb) {
        unsigned m0 = bcast_rec(r0, r1, j);
        int s0 = (int)(m0 >> 16);
        float sc0 = m1 ? ((float)(m0 & 0xFFFFu) + 0.5f) * Q : rsqrtf(deg[s0]);
        float4 v0 = h4[(size_t)s0 * 32 + lane];
        a0 += v0.x * sc0; a1 += v0.y * sc0; a2 += v0.z * sc0; a3 += v0.w * sc0;
    }
    a0 += b0; a1 += b1; a2 += b2; a3 += b3;
    if (cnt > cap) {
        int total = *ovfcnt;
        for (int k = 0; k < total; ++k) {
            int e = ovf[k];
            if (dst[e] == node) {
                int s = src[e];
                float sc = m1 ? w[e] : rsqrtf(deg[s]);
                float4 v = ((const float4*)(h + (long long)s * D_FEAT))[lane];
                a0 += v.x * sc; a1 += v.y * sc; a2 += v.z * sc; a3 += v.w * sc;
            }
        }
    }
    float fin = m1 ? 1.0f : rsqrtf(deg[node]);
    float4 r; r.x = a0 * fin; r.y = a1 * fin; r.z = a2 * fin; r.w = a3 * fin;
    ((float4*)(out + (long long)node * D_FEAT))[lane] = r;
}

// ================= PATH C: 8B records (smaller ws) =================

__global__ void bucket_direct_kernel(const int* __restrict__ src, const int* __restrict__ dst,
                                     const float* __restrict__ w,
                                     int* __restrict__ cursor, float* __restrict__ deg,
                                     int* __restrict__ ovfcnt, int* __restrict__ ovf,
                                     uint2* __restrict__ epack, int cap,
                                     int E, const int* __restrict__ mode) {
    int e = blockIdx.x * blockDim.x + threadIdx.x;
    if (e >= E) return;
    bool m1 = (*mode == 1);
    int d = dst[e];
    int s = src[e];
    if (!m1) atomicAdd(&deg[s], 1.0f);
    int pos = atomicAdd(&cursor[d], 1);
    if (pos < cap) {
        float sc = m1 ? w[e] : 0.0f;
        epack[(size_t)d * cap + pos] = make_uint2((unsigned)s, __float_as_uint(sc));
    } else {
        ovf[atomicAdd(ovfcnt, 1)] = e;
    }
}

__global__ void gather_cap_kernel(const float* __restrict__ h,
                                  const int* __restrict__ cursor, const float* __restrict__ deg,
                                  const uint2* __restrict__ epack, int cap,
                                  const int* __restrict__ ovfcnt, const int* __restrict__ ovf,
                                  const int* __restrict__ src, const int* __restrict__ dst,
                                  const float* __restrict__ w,
                                  float* __restrict__ out, int N, const int* __restrict__ mode) {
    long long gid = (long long)blockIdx.x * blockDim.x + threadIdx.x;
    int node = (int)(gid >> 5);
    int lane = (int)(gid & 31);
    if (node >= N) return;
    bool m1 = (*mode == 1);
    int cnt = cursor[node];
    int inb = cnt < cap ? cnt : cap;
    const uint2* row = epack + (size_t)node * cap;
    float a0 = 0.f, a1 = 0.f, a2 = 0.f, a3 = 0.f;
    for (int j = 0; j < inb; ++j) {
        uint2 m = row[j];
        int s = (int)m.x;
        float sc = m1 ? __uint_as_float(m.y) : rsqrtf(deg[s]);
        float4 v = ((const float4*)(h + (long long)s * D_FEAT))[lane];
        a0 += v.x * sc; a1 += v.y * sc; a2 += v.z * sc; a3 += v.w * sc;
    }
    if (cnt > cap) {
        int total = *ovfcnt;
        for (int k = 0; k < total; ++k) {
            int e = ovf[k];
            if (dst[e] == node) {
                int s = src[e];
                float sc = m1 ? w[e] : rsqrtf(deg[s]);
                float4 v = ((const float4*)(h + (long long)s * D_FEAT))[lane];
                a0 += v.x * sc; a1 += v.y * sc; a2 += v.z * sc; a3 += v.w * sc;
            }
        }
    }
    float fin = m1 ? 1.0f : rsqrtf(deg[node]);
    float4 r; r.x = a0 * fin; r.y = a1 * fin; r.z = a2 * fin; r.w = a3 * fin;
    ((float4*)(out + (long long)node * D_FEAT))[lane] = r;
}

// ================= ultra-fallback: atomic scatter =================

__global__ void fb_deg_kernel(const int* __restrict__ src, float* __restrict__ deg,
                              int E, const int* __restrict__ mode) {
    if (*mode == 1) return;
    int e = blockIdx.x * blockDim.x + threadIdx.x;
    if (e < E) atomicAdd(&deg[src[e]], 1.0f);
}
__global__ void fb_norm_kernel(const float* __restrict__ deg, float* __restrict__ norm,
                               int N, const int* __restrict__ mode) {
    if (*mode == 1) return;
    int i = blockIdx.x * blockDim.x + threadIdx.x;
    if (i < N) norm[i] = rsqrtf(deg[i]);
}
__global__ void fb_scatter_kernel(const float* __restrict__ h, const float* __restrict__ w,
                                  const int* __restrict__ src, const int* __restrict__ dst,
                                  const float* __restrict__ norm, float* __restrict__ out,
                                  int E, const int* __restrict__ mode) {
    long long gid = (long long)blockIdx.x * blockDim.x + threadIdx.x;
    int e = (int)(gid >> 5);
    int lane = (int)(gid & 31);
    if (e >= E) return;
    int s = src[e], d = dst[e];
    float scale = (*mode == 1) ? w[e] : norm[s];
    float4 v = ((const float4*)(h + (long long)s * D_FEAT))[lane];
    float* op = out + (long long)d * D_FEAT + lane * 4;
    atomicAdd(op + 0, v.x * scale);
    atomicAdd(op + 1, v.y * scale);
    atomicAdd(op + 2, v.z * scale);
    atomicAdd(op + 3, v.w * scale);
}
__global__ void fb_scale_kernel(float* __restrict__ out, const float* __restrict__ norm,
                                int N, const int* __restrict__ mode) {
    if (*mode == 1) return;
    int idx = blockIdx.x * blockDim.x + threadIdx.x;
    int total = N * (D_FEAT / 4);
    if (idx >= total) return;
    int node = idx / (D_FEAT / 4);
    float4* op = (float4*)out + idx;
    float4 v = *op;
    float nn = norm[node];
    v.x *= nn; v.y *= nn; v.z *= nn; v.w *= nn;
    *op = v;
}

// ================= host =================

extern "C" void kernel_launch(void* const* d_in, const int* in_sizes, int n_in,
                              void* d_out, int out_size, void* d_ws, size_t ws_size,
                              hipStream_t stream) {
    const float* h    = (const float*)d_in[0];
    const float* w    = (const float*)d_in[1];
    const int*   src  = (const int*)d_in[2];
    const int*   dst  = (const int*)d_in[3];
    const int*   mode = (const int*)d_in[4];

    int ND = in_sizes[0];
    int E  = in_sizes[1];
    int N  = ND / D_FEAT;

    float* out = (float*)d_out;

    size_t ws_words = ws_size / 4;

    // ---------- fp16 path: padded cursor + h16 cache + 4B records ----------
    // try cursor stride 16 (1 counter / 64B line), then 4, then 1
    for (int cs : {16, 4, 1}) {
        size_t cur_words   = (size_t)N * cs;
        size_t fixed_words = cur_words + (size_t)N + 1 + (size_t)E;  // cursor,deg,ovfcnt,ovf
        size_t h16_off     = (fixed_words + 3) & ~(size_t)3;         // 16B align
        size_t h16_words   = (size_t)N * (D_FEAT / 2);               // N*128 halfs
        size_t rec16_off   = h16_off + h16_words;
        long capH = 0;
        if (ws_words > rec16_off) capH = (long)((ws_words - rec16_off) / (size_t)N);
        if (capH > 64) capH = 64;

        if (N <= 65536 && capH >= 28) {
            int*      cursor = (int*)d_ws;
            float*    deg    = (float*)(cursor + cur_words);
            int*      ovfcnt = (int*)(deg + N);
            int*      ovf    = ovfcnt + 1;
            uint4*    h16    = (uint4*)((int*)d_ws + h16_off);
            unsigned* rec    = (unsigned*)((int*)d_ws + rec16_off);
            int cap = (int)capH;

            hipMemsetAsync(d_ws, 0, (cur_words + (size_t)N + 1) * sizeof(int), stream);

            int nGroups8    = ND / 8;                      // 8 floats per convert thread
            int nBucketBlks = (E + 255) / 256;             // 1 edge/thread -> max waves
            int nConvBlks   = (nGroups8 + 255) / 256;
            bucket_conv_kernel<<<nBucketBlks + nConvBlks, 256, 0, stream>>>(
                h, src, dst, w, cursor, deg, ovfcnt, ovf, rec, cap, h16,
                E, nBucketBlks, nGroups8, cs, mode);

            long long gt = (long long)N * 32;
            gather4_f16_kernel<<<(int)((gt + 255) / 256), 256, 0, stream>>>(
                (const uint2*)h16, h, cursor, deg, rec, cap, ovfcnt, ovf, src, dst, w,
                out, N, cs, mode);
            return;
        }
    }

    size_t fixed_words = 2 * (size_t)N + 1 + (size_t)E;
    int*   cursor = (int*)d_ws;
    float* deg    = (float*)(cursor + N);
    int*   ovfcnt = (int*)(deg + N);
    int*   ovf    = ovfcnt + 1;

    // ---------- f32 path: 4B records, no h16 ----------
    size_t rec_off = fixed_words;
    long capA = 0;
    if (ws_words > rec_off) capA = (long)((ws_words - rec_off) / (size_t)N);
    if (capA > 64) capA = 64;

    if (N <= 65536 && capA >= 28) {
        unsigned* rec = (unsigned*)((int*)d_ws + rec_off);
        int cap = (int)capA;
        hipMemsetAsync(d_ws, 0, (2 * (size_t)N + 1) * sizeof(int), stream);
        int nthreads = (E + 3) / 4;
        bucket_multi_kernel<<<(nthreads + 255) / 256, 256, 0, stream>>>(
            src, dst, w, cursor, deg, ovfcnt, ovf, rec, cap, E, mode);
        long long gt = (long long)N * 32;
        gather4_f32_kernel<<<(int)((gt + 255) / 256), 256, 0, stream>>>(
            h, cursor, deg, rec, cap, ovfcnt, ovf, src, dst, w, out, N, mode);
        return;
    }

    // ---------- PATH C: 8B records ----------
    size_t epack_off = (fixed_words + 1) & ~(size_t)1;
    long capC = 0;
    if (ws_words > epack_off) capC = (long)((ws_words - epack_off) / (2 * (size_t)N));
    if (capC > 64) capC = 64;

    if (capC >= 8) {
        uint2* epack = (uint2*)((int*)d_ws + epack_off);
        hipMemsetAsync(d_ws, 0, (2 * (size_t)N + 1) * sizeof(int), stream);
        bucket_direct_kernel<<<(E + 255) / 256, 256, 0, stream>>>(
            src, dst, w, cursor, deg, ovfcnt, ovf, epack, (int)capC, E, mode);
        long long gt = (long long)N * 32;
        gather_cap_kernel<<<(int)((gt + 255) / 256), 256, 0, stream>>>(
            h, cursor, deg, epack, (int)capC, ovfcnt, ovf, src, dst, w, out, N, mode);
        return;
    }

    // ---------- ultra-fallback: atomic scatter ----------
    float* degF  = (float*)d_ws;
    float* normF = degF + N;
    hipMemsetAsync(d_out, 0, (size_t)out_size * sizeof(float), stream);
    hipMemsetAsync(d_ws, 0, (size_t)N * sizeof(float), stream);
    fb_deg_kernel<<<(E + 255) / 256, 256, 0, stream>>>(src, degF, E, mode);
    fb_norm_kernel<<<(N + 255) / 256, 256, 0, stream>>>(degF, normF, N, mode);
    long long tt = (long long)E * 32;
    fb_scatter_kernel<<<(int)((tt + 255) / 256), 256, 0, stream>>>(h, w, src, dst,
                                                                   normF, out, E, mode);
    int st = N * (D_FEAT / 4);
    fb_scale_kernel<<<(st + 255) / 256, 256, 0, stream>>>(out, normF, N, mode);
}